// Round 2
// baseline (392.831 us; speedup 1.0000x reference)
//
#include <hip/hip_runtime.h>

#define IPB 20        // items per block
#define NT 512        // threads per block (500 active)
#define NQ 25
#define KVD 9
#define WPAD 12       // padded weight row (floats) -> 48 B, 16B aligned
#define KVROW 24      // k at [0..9), v at [12..21), per token row (96 B)
#define QSCALE 0.4808983469629878f   /* log2(e)/3 : folds softmax 1/sqrt(9) and exp->exp2 */
#define MSCALE (-1.4426950408889634e9f) /* -1e9 * log2(e) */

// dot product of 9 floats (w from LDS, xv in regs), seeded accumulator
__device__ __forceinline__ float dot9(const float* __restrict__ w,
                                      const float* __restrict__ xv, float acc) {
  float4 a = *(const float4*)(w);
  float4 b = *(const float4*)(w + 4);
  float c = w[8];
  acc = fmaf(a.x, xv[0], acc);
  acc = fmaf(a.y, xv[1], acc);
  acc = fmaf(a.z, xv[2], acc);
  acc = fmaf(a.w, xv[3], acc);
  acc = fmaf(b.x, xv[4], acc);
  acc = fmaf(b.y, xv[5], acc);
  acc = fmaf(b.z, xv[6], acc);
  acc = fmaf(b.w, xv[7], acc);
  acc = fmaf(c,   xv[8], acc);
  return acc;
}

__global__ __launch_bounds__(NT, 6) void attn_fused(
    const float* __restrict__ x, const float* __restrict__ mask,
    const float* __restrict__ Wq, const float* __restrict__ bq,
    const float* __restrict__ Wk, const float* __restrict__ bk,
    const float* __restrict__ Wv, const float* __restrict__ bv,
    const float* __restrict__ gamma, const float* __restrict__ beta,
    float* __restrict__ out, int B) {
  __shared__ __align__(16) float sW[3][4][KVD][WPAD];  // [q/k/v][group][row][d]
  __shared__ __align__(16) float sB[3][4][KVD];
  __shared__ __align__(16) float sMask[NQ];
  __shared__ __align__(16) float sG[KVD];
  __shared__ __align__(16) float sBeta[KVD];
  __shared__ __align__(16) float sKV[IPB][NQ][KVROW];  // 20*25*24*4 = 48000 B

  const int tid = threadIdx.x;
  const int il = tid / NQ;
  const int tk = tid - il * NQ;
  const long item = (long)blockIdx.x * IPB + il;
  const bool active = (tid < IPB * NQ) && (item < (long)B);

  // ---- prefetch x BEFORE staging: HBM latency hides behind weight staging ----
  float xv[KVD];
  if (active) {
    const float* xp = x + item * 225 + tk * KVD;
#pragma unroll
    for (int d = 0; d < KVD; ++d) xv[d] = xp[d];
  }

  // ---- stage parameters into LDS (q-weights/bias pre-scaled by log2e/3) ----
  for (int i = tid; i < 324; i += NT) {  // 4*9*9 per matrix
    int g = i / 81;
    int r = (i - g * 81) / 9;
    int d = i - g * 81 - r * 9;
    sW[0][g][r][d] = Wq[i] * QSCALE;
    sW[1][g][r][d] = Wk[i];
    sW[2][g][r][d] = Wv[i];
  }
  for (int i = tid; i < 36; i += NT) {
    int g = i / 9, d = i - g * 9;
    sB[0][g][d] = bq[i] * QSCALE;
    sB[1][g][d] = bk[i];
    sB[2][g][d] = bv[i];
  }
  if (tid < NQ) sMask[tid] = mask[tid] * MSCALE;
  if (tid < KVD) { sG[tid] = gamma[tid]; sBeta[tid] = beta[tid]; }
  __syncthreads();

  float q[KVD];
  if (active) {
    const int g = (tk < 3) ? 0 : (tk < 13) ? 1 : (tk < 23) ? 2 : 3;
    const float* wq = &sW[0][g][0][0];
    const float* wk = &sW[1][g][0][0];
    const float* wv = &sW[2][g][0][0];

    float kr[KVD], vr[KVD];
#pragma unroll
    for (int e = 0; e < KVD; ++e) {
      q[e]  = dot9(wq + e * WPAD, xv, sB[0][g][e]);  // pre-scaled by log2e/3
      kr[e] = dot9(wk + e * WPAD, xv, sB[1][g][e]);
      vr[e] = dot9(wv + e * WPAD, xv, sB[2][g][e]);
    }
    float* kvp = &sKV[il][tk][0];
    *(float4*)(kvp)      = make_float4(kr[0], kr[1], kr[2], kr[3]);
    *(float4*)(kvp + 4)  = make_float4(kr[4], kr[5], kr[6], kr[7]);
    kvp[8] = kr[8];
    *(float4*)(kvp + 12) = make_float4(vr[0], vr[1], vr[2], vr[3]);
    *(float4*)(kvp + 16) = make_float4(vr[4], vr[5], vr[6], vr[7]);
    kvp[20] = vr[8];
  }
  __syncthreads();

  if (active) {
    const float* kvb = &sKV[il][0][0];
    // scores in log2 domain: t_j = (q.k)*log2e/3 + mask_j*(-1e9*log2e)
    float s[NQ];
    float m = -3.4e38f;
#pragma unroll
    for (int j = 0; j < NQ; ++j) {
      float sc = dot9(kvb + j * KVROW, q, sMask[j]);
      s[j] = sc;
      m = fmaxf(m, sc);
    }
    float sum = 0.f;
#pragma unroll
    for (int j = 0; j < NQ; ++j) {
      float p = __builtin_amdgcn_exp2f(s[j] - m);
      s[j] = p;
      sum += p;
    }
    const float inv = __builtin_amdgcn_rcpf(sum);

    float o[KVD];
#pragma unroll
    for (int d = 0; d < KVD; ++d) o[d] = 0.f;
#pragma unroll
    for (int j = 0; j < NQ; ++j) {
      const float* vp = kvb + j * KVROW + 12;
      float4 a = *(const float4*)(vp);
      float4 b = *(const float4*)(vp + 4);
      float c = vp[8];
      const float p = s[j];
      o[0] = fmaf(p, a.x, o[0]);
      o[1] = fmaf(p, a.y, o[1]);
      o[2] = fmaf(p, a.z, o[2]);
      o[3] = fmaf(p, a.w, o[3]);
      o[4] = fmaf(p, b.x, o[4]);
      o[5] = fmaf(p, b.y, o[5]);
      o[6] = fmaf(p, b.z, o[6]);
      o[7] = fmaf(p, b.w, o[7]);
      o[8] = fmaf(p, c,   o[8]);
    }

    // residual + LayerNorm (one pass: sum & sumsq)
    float r[KVD];
    float sm = 0.f, sq = 0.f;
#pragma unroll
    for (int d = 0; d < KVD; ++d) {
      r[d] = fmaf(o[d], inv, xv[d]);
      sm += r[d];
      sq = fmaf(r[d], r[d], sq);
    }
    const float mu = sm * (1.0f / 9.0f);
    float var = fmaf(mu, -mu, sq * (1.0f / 9.0f));
    const float rs = __builtin_amdgcn_rsqf(var + 1e-5f);
    float* op = out + item * 225 + tk * KVD;
#pragma unroll
    for (int d = 0; d < KVD; ++d)
      op[d] = fmaf((r[d] - mu) * rs, sG[d], sBeta[d]);
  }
}

extern "C" void kernel_launch(void* const* d_in, const int* in_sizes, int n_in,
                              void* d_out, int out_size, void* d_ws, size_t ws_size,
                              hipStream_t stream) {
  const float* x     = (const float*)d_in[0];
  const float* mask  = (const float*)d_in[1];
  const float* Wq    = (const float*)d_in[2];
  const float* bq    = (const float*)d_in[3];
  const float* Wk    = (const float*)d_in[4];
  const float* bk    = (const float*)d_in[5];
  const float* Wv    = (const float*)d_in[6];
  const float* bv    = (const float*)d_in[7];
  const float* gamma = (const float*)d_in[8];
  const float* beta  = (const float*)d_in[9];
  float* out = (float*)d_out;
  const int B = in_sizes[0] / 225;
  const int grid = (B + IPB - 1) / IPB;
  attn_fused<<<grid, NT, 0, stream>>>(x, mask, Wq, bq, Wk, bk, Wv, bv,
                                      gamma, beta, out, B);
}

// Round 3
// 265.928 us; speedup vs baseline: 1.4772x; 1.4772x over previous
//
#include <hip/hip_runtime.h>

#define IPB 10        // items per block (250 of 256 lanes active)
#define NT 256
#define NQ 25
#define KVD 9
#define QSCALE 0.4808983469629878f      /* log2(e)/3 : folds 1/sqrt(9) and exp->exp2 */
#define MSCALE (-1.4426950408889634e9f) /* -1e9 * log2(e) */

// dot of 8 floats from LDS (two b128) against xv[0..7], seeded
__device__ __forceinline__ float dot8(const float* __restrict__ w,
                                      const float* __restrict__ xv, float acc) {
  float4 a = *(const float4*)(w);
  float4 b = *(const float4*)(w + 4);
  acc = fmaf(a.x, xv[0], acc);
  acc = fmaf(a.y, xv[1], acc);
  acc = fmaf(a.z, xv[2], acc);
  acc = fmaf(a.w, xv[3], acc);
  acc = fmaf(b.x, xv[4], acc);
  acc = fmaf(b.y, xv[5], acc);
  acc = fmaf(b.z, xv[6], acc);
  acc = fmaf(b.w, xv[7], acc);
  return acc;
}

// 9-dim projection: out[e] = bias[e] + sum_d W[e][d]*xv[d], W split as 8+1
__device__ __forceinline__ void proj9(const float* __restrict__ w8,
                                      const float* __restrict__ w9,
                                      const float* __restrict__ bias,
                                      const float* __restrict__ xv,
                                      float* __restrict__ outv) {
  float4 na = *(const float4*)(w9);
  float4 nb = *(const float4*)(w9 + 4);
  float  nc = w9[8];
  float4 ba = *(const float4*)(bias);
  float4 bb = *(const float4*)(bias + 4);
  float  bc = bias[8];
  const float w9e[9]  = {na.x, na.y, na.z, na.w, nb.x, nb.y, nb.z, nb.w, nc};
  const float seed[9] = {ba.x, ba.y, ba.z, ba.w, bb.x, bb.y, bb.z, bb.w, bc};
#pragma unroll
  for (int e = 0; e < KVD; ++e)
    outv[e] = dot8(w8 + e * 8, xv, fmaf(w9e[e], xv[8], seed[e]));
}

__global__ __launch_bounds__(NT) void attn_fused(
    const float* __restrict__ x, const float* __restrict__ mask,
    const float* __restrict__ Wq, const float* __restrict__ bq,
    const float* __restrict__ Wk, const float* __restrict__ bk,
    const float* __restrict__ Wv, const float* __restrict__ bv,
    const float* __restrict__ gamma, const float* __restrict__ beta,
    float* __restrict__ out, int B) {
  // weights split: 8-float rows (b128-friendly) + packed 9th column
  __shared__ __align__(16) float sW8[3][4][KVD][8];   // 3456 B
  __shared__ __align__(16) float sW9[3][4][12];       //  576 B
  __shared__ __align__(16) float sBias[3][4][12];     //  576 B
  __shared__ __align__(16) float sMask[28];           //  112 B
  __shared__ __align__(16) float sG[12];
  __shared__ __align__(16) float sBt[12];
  __shared__ __align__(16) float sK8[IPB][NQ][8];     // 8000 B
  __shared__ __align__(16) float sK9[IPB][28];        // 1120 B
  __shared__ __align__(16) float sV8[IPB][NQ][8];     // 8000 B
  __shared__ __align__(16) float sV9[IPB][28];        // 1120 B
  // total ~23 KB -> 6 blocks/CU = 24 waves (75% cap)

  const int tid = threadIdx.x;
  const int il = tid / NQ;
  const int tk = tid - il * NQ;
  const long item = (long)blockIdx.x * IPB + il;
  const bool active = (tid < IPB * NQ) && (item < (long)B);

  // ---- prefetch x before staging: HBM latency hides behind weight staging ----
  float xv[KVD];
  if (active) {
    const float* xp = x + item * 225 + tk * KVD;
#pragma unroll
    for (int d = 0; d < KVD; ++d) xv[d] = xp[d];
  }

  // ---- stage parameters (q pre-scaled by log2e/3) ----
  for (int i = tid; i < 324; i += NT) {  // 4*9*9
    int g = i / 81;
    int r = i - g * 81;
    int e = r / 9;
    int d = r - e * 9;
    float a = Wq[i] * QSCALE, b = Wk[i], c = Wv[i];
    if (d < 8) {
      sW8[0][g][e][d] = a; sW8[1][g][e][d] = b; sW8[2][g][e][d] = c;
    } else {
      sW9[0][g][e] = a; sW9[1][g][e] = b; sW9[2][g][e] = c;
    }
  }
  for (int i = tid; i < 36; i += NT) {
    int g = i / 9, d = i - g * 9;
    sBias[0][g][d] = bq[i] * QSCALE;
    sBias[1][g][d] = bk[i];
    sBias[2][g][d] = bv[i];
  }
  if (tid < NQ) sMask[tid] = mask[tid] * MSCALE;
  if (tid < KVD) { sG[tid] = gamma[tid]; sBt[tid] = beta[tid]; }
  __syncthreads();

  float q[KVD];
  if (active) {
    const int g = (tk < 3) ? 0 : (tk < 13) ? 1 : (tk < 23) ? 2 : 3;
    float kr[KVD], vr[KVD];
    proj9(&sW8[0][g][0][0], &sW9[0][g][0], &sBias[0][g][0], xv, q);
    proj9(&sW8[1][g][0][0], &sW9[1][g][0], &sBias[1][g][0], xv, kr);
    proj9(&sW8[2][g][0][0], &sW9[2][g][0], &sBias[2][g][0], xv, vr);
    *(float4*)&sK8[il][tk][0] = make_float4(kr[0], kr[1], kr[2], kr[3]);
    *(float4*)&sK8[il][tk][4] = make_float4(kr[4], kr[5], kr[6], kr[7]);
    sK9[il][tk] = kr[8];
    *(float4*)&sV8[il][tk][0] = make_float4(vr[0], vr[1], vr[2], vr[3]);
    *(float4*)&sV8[il][tk][4] = make_float4(vr[4], vr[5], vr[6], vr[7]);
    sV9[il][tk] = vr[8];
  }
  __syncthreads();

  if (active) {
    const float* kb = &sK8[il][0][0];
    const float* k9 = &sK9[il][0];
    const float* vb = &sV8[il][0][0];
    const float* v9 = &sV9[il][0];

    // seed scores with pre-scaled mask (float4 chunks)
    float s[NQ];
    {
      float4 mc;
      mc = *(const float4*)(sMask + 0);  s[0]=mc.x;  s[1]=mc.y;  s[2]=mc.z;  s[3]=mc.w;
      mc = *(const float4*)(sMask + 4);  s[4]=mc.x;  s[5]=mc.y;  s[6]=mc.z;  s[7]=mc.w;
      mc = *(const float4*)(sMask + 8);  s[8]=mc.x;  s[9]=mc.y;  s[10]=mc.z; s[11]=mc.w;
      mc = *(const float4*)(sMask + 12); s[12]=mc.x; s[13]=mc.y; s[14]=mc.z; s[15]=mc.w;
      mc = *(const float4*)(sMask + 16); s[16]=mc.x; s[17]=mc.y; s[18]=mc.z; s[19]=mc.w;
      mc = *(const float4*)(sMask + 20); s[20]=mc.x; s[21]=mc.y; s[22]=mc.z; s[23]=mc.w;
      mc = *(const float4*)(sMask + 24); s[24]=mc.x;
    }
#pragma unroll
    for (int j = 0; j < NQ; ++j) s[j] = dot8(kb + j * 8, q, s[j]);
    const float q8 = q[8];
#pragma unroll
    for (int c = 0; c < 6; ++c) {
      float4 kc = *(const float4*)(k9 + 4 * c);
      s[4*c+0] = fmaf(q8, kc.x, s[4*c+0]);
      s[4*c+1] = fmaf(q8, kc.y, s[4*c+1]);
      s[4*c+2] = fmaf(q8, kc.z, s[4*c+2]);
      s[4*c+3] = fmaf(q8, kc.w, s[4*c+3]);
    }
    s[24] = fmaf(q8, k9[24], s[24]);

    float m = s[0];
#pragma unroll
    for (int j = 1; j < NQ; ++j) m = fmaxf(m, s[j]);
    float sum = 0.f;
#pragma unroll
    for (int j = 0; j < NQ; ++j) {
      float p = __builtin_amdgcn_exp2f(s[j] - m);
      s[j] = p;
      sum += p;
    }
    const float inv = __builtin_amdgcn_rcpf(sum);

    float o[KVD];
#pragma unroll
    for (int d = 0; d < KVD; ++d) o[d] = 0.f;
#pragma unroll
    for (int j = 0; j < NQ; ++j) {
      float4 a = *(const float4*)(vb + j * 8);
      float4 b = *(const float4*)(vb + j * 8 + 4);
      const float p = s[j];
      o[0] = fmaf(p, a.x, o[0]);
      o[1] = fmaf(p, a.y, o[1]);
      o[2] = fmaf(p, a.z, o[2]);
      o[3] = fmaf(p, a.w, o[3]);
      o[4] = fmaf(p, b.x, o[4]);
      o[5] = fmaf(p, b.y, o[5]);
      o[6] = fmaf(p, b.z, o[6]);
      o[7] = fmaf(p, b.w, o[7]);
    }
#pragma unroll
    for (int c = 0; c < 6; ++c) {
      float4 vc = *(const float4*)(v9 + 4 * c);
      o[8] = fmaf(s[4*c+0], vc.x, o[8]);
      o[8] = fmaf(s[4*c+1], vc.y, o[8]);
      o[8] = fmaf(s[4*c+2], vc.z, o[8]);
      o[8] = fmaf(s[4*c+3], vc.w, o[8]);
    }
    o[8] = fmaf(s[24], v9[24], o[8]);

    // gamma/beta chunked
    float4 ga = *(const float4*)(sG);
    float4 gb = *(const float4*)(sG + 4);
    float  gc = sG[8];
    float4 ta = *(const float4*)(sBt);
    float4 tb = *(const float4*)(sBt + 4);
    float  tc = sBt[8];
    const float gg[9] = {ga.x, ga.y, ga.z, ga.w, gb.x, gb.y, gb.z, gb.w, gc};
    const float bb[9] = {ta.x, ta.y, ta.z, ta.w, tb.x, tb.y, tb.z, tb.w, tc};

    // residual + one-pass LayerNorm
    float r[KVD];
    float sm = 0.f, sq = 0.f;
#pragma unroll
    for (int d = 0; d < KVD; ++d) {
      r[d] = fmaf(o[d], inv, xv[d]);
      sm += r[d];
      sq = fmaf(r[d], r[d], sq);
    }
    const float mu = sm * (1.0f / 9.0f);
    float var = fmaf(mu, -mu, sq * (1.0f / 9.0f));
    const float rs = __builtin_amdgcn_rsqf(var + 1e-5f);
    float* op = out + item * 225 + tk * KVD;
#pragma unroll
    for (int d = 0; d < KVD; ++d)
      op[d] = fmaf((r[d] - mu) * rs, gg[d], bb[d]);
  }
}

extern "C" void kernel_launch(void* const* d_in, const int* in_sizes, int n_in,
                              void* d_out, int out_size, void* d_ws, size_t ws_size,
                              hipStream_t stream) {
  const float* x     = (const float*)d_in[0];
  const float* mask  = (const float*)d_in[1];
  const float* Wq    = (const float*)d_in[2];
  const float* bq    = (const float*)d_in[3];
  const float* Wk    = (const float*)d_in[4];
  const float* bk    = (const float*)d_in[5];
  const float* Wv    = (const float*)d_in[6];
  const float* bv    = (const float*)d_in[7];
  const float* gamma = (const float*)d_in[8];
  const float* beta  = (const float*)d_in[9];
  float* out = (float*)d_out;
  const int B = in_sizes[0] / 225;
  const int grid = (B + IPB - 1) / IPB;
  attn_fused<<<grid, NT, 0, stream>>>(x, mask, Wq, bq, Wk, bk, Wv, bv,
                                      gamma, beta, out, B);
}